// Round 2
// baseline (1081.769 us; speedup 1.0000x reference)
//
#include <hip/hip_runtime.h>
#include <hip/hip_bf16.h>
#include <cstdint>
#include <cstddef>

// Problem constants
#define TT  512
#define BB  256
#define DIN 512
#define HH  128
#define NG  512   // 4*H

typedef __bf16 bf16x8 __attribute__((ext_vector_type(8)));
typedef __bf16 bf16x4 __attribute__((ext_vector_type(4)));
typedef float  f32x4  __attribute__((ext_vector_type(4)));

__device__ __forceinline__ float fast_sig(float x) {
  float e = __builtin_amdgcn_exp2f(-1.44269504f * x);   // e^-x
  return __builtin_amdgcn_rcpf(1.0f + e);
}
__device__ __forceinline__ float fast_tanh(float x) {
  float e = __builtin_amdgcn_exp2f(-2.88539008f * x);   // e^-2x
  return 2.0f * __builtin_amdgcn_rcpf(1.0f + e) - 1.0f;
}

// Barrier with LDS-visibility only: does NOT drain vmcnt, so global loads
// (prefetch) and posted stores stay in flight across the barrier.
__device__ __forceinline__ void lgkm_barrier() {
  asm volatile("s_waitcnt lgkmcnt(0)\n\ts_barrier" ::: "memory");
}

// ---------------- P0: weight transpose + fp32->bf16 convert ----------------
__global__ void wconv_kernel(const float* __restrict__ Wi, const float* __restrict__ Wh,
                             __bf16* __restrict__ WiT, __bf16* __restrict__ WhT) {
  int idx = blockIdx.x * 256 + threadIdx.x;
  if (idx < DIN * NG) {
    int n = idx >> 9, k = idx & 511;
    WiT[(size_t)n * DIN + k] = (__bf16)Wi[(size_t)k * NG + n];
  }
  if (idx < HH * NG) {
    int n = idx >> 7, k = idx & 127;
    WhT[(size_t)n * HH + k] = (__bf16)Wh[(size_t)k * NG + n];
  }
}

// ---------------- P1: Xg = obs @ Wi + b  (bf16 out, scan-friendly layout) --
// Xg layout: [T][bg=B/16][n=512][bl=16] bf16  (128 MiB)
// Software-pipelined: A (fp32->bf16) and B staged via regs one K-iter ahead;
// both barriers are lgkm-only so the K-loop never drains vmcnt.
#define BK 32
__global__ __launch_bounds__(512, 2)
void gemm_kernel(const float* __restrict__ obs, const __bf16* __restrict__ WiT,
                 const float* __restrict__ bias, __bf16* __restrict__ Xg) {
  __shared__ __bf16 Alds[128][BK + 8];   // 80B rows: frag reads 2-way (free)
  __shared__ __bf16 Blds[NG][BK + 8];
  const int tid  = threadIdx.x;
  const int wave = tid >> 6;
  const int lane = tid & 63;
  const int l15  = lane & 15, q = lane >> 4;
  const size_t m0 = (size_t)blockIdx.x * 128;

  const f32x4 fzero = {0.f, 0.f, 0.f, 0.f};
  f32x4 acc[8][4];
#pragma unroll
  for (int i = 0; i < 8; i++)
#pragma unroll
    for (int jj = 0; jj < 4; jj++) acc[i][jj] = fzero;

  const int am = tid >> 2, aq = tid & 3;  // A staging: row, 8-float quarter of BK
  const float* aptr = obs + (m0 + am) * DIN + aq * 8;
  const __bf16* bptr = WiT + (size_t)tid * DIN;

  // prologue: prefetch iter 0
  float4 a0 = ((const float4*)aptr)[0];
  float4 a1 = ((const float4*)aptr)[1];
  uint4 b0 = ((const uint4*)bptr)[0];
  uint4 b1 = ((const uint4*)bptr)[1];
  uint4 b2 = ((const uint4*)bptr)[2];
  uint4 b3 = ((const uint4*)bptr)[3];

  for (int kc = 0; kc < DIN; kc += BK) {
    if (kc) lgkm_barrier();              // prev compute done reading LDS
    { // store staged tiles (compiler waits vmcnt on reg use here)
      bf16x8 v = {(__bf16)a0.x, (__bf16)a0.y, (__bf16)a0.z, (__bf16)a0.w,
                  (__bf16)a1.x, (__bf16)a1.y, (__bf16)a1.z, (__bf16)a1.w};
      *(bf16x8*)&Alds[am][aq * 8] = v;
      uint4* dst = (uint4*)&Blds[tid][0];
      dst[0] = b0; dst[1] = b1; dst[2] = b2; dst[3] = b3;
    }
    lgkm_barrier();                      // stores visible; vmcnt untouched
    if (kc + BK < DIN) {                 // prefetch next iter during compute
      const float* ap = aptr + kc + BK;
      a0 = ((const float4*)ap)[0];
      a1 = ((const float4*)ap)[1];
      const uint4* bp = (const uint4*)(bptr + kc + BK);
      b0 = bp[0]; b1 = bp[1]; b2 = bp[2]; b3 = bp[3];
    }
    bf16x8 bfr[4];
#pragma unroll
    for (int nt = 0; nt < 4; nt++)
      bfr[nt] = *(const bf16x8*)&Blds[wave * 64 + nt * 16 + l15][q * 8];
#pragma unroll
    for (int mt = 0; mt < 8; mt++) {
      bf16x8 af = *(const bf16x8*)&Alds[mt * 16 + l15][q * 8];
#pragma unroll
      for (int nt = 0; nt < 4; nt++)
        acc[mt][nt] = __builtin_amdgcn_mfma_f32_16x16x32_bf16(af, bfr[nt], acc[mt][nt], 0, 0, 0);
    }
  }
  // epilogue: C row = mt*16 + q*4 + r (batch-local), col n = wave*64 + nt*16 + l15
  const int t = blockIdx.x >> 1;
  const int bbase = (blockIdx.x & 1) * 128;
#pragma unroll
  for (int mt = 0; mt < 8; mt++) {
    int bloc = bbase + mt * 16 + q * 4;
    int bg = bloc >> 4, bl = bloc & 15;
#pragma unroll
    for (int nt = 0; nt < 4; nt++) {
      int n = wave * 64 + nt * 16 + l15;
      float bb = bias[n];
      bf16x4 v = {(__bf16)(acc[mt][nt][0] + bb), (__bf16)(acc[mt][nt][1] + bb),
                  (__bf16)(acc[mt][nt][2] + bb), (__bf16)(acc[mt][nt][3] + bb)};
      *(bf16x4*)(Xg + (((size_t)t * 16 + bg) * NG + n) * 16 + bl) = v;
    }
  }
}

// ---------------- P2: sequential scan, 16 persistent blocks (1/batch-group) -
// Double-buffered h in LDS -> ONE lgkm-only barrier per step; Xg/done
// prefetched at distance 2; no vmcnt drain anywhere in the loop.
__global__ __launch_bounds__(512, 2)
void scan_kernel(const __bf16* __restrict__ Xg, const __bf16* __restrict__ WhT,
                 const int* __restrict__ done, const float* __restrict__ c0,
                 const float* __restrict__ h0, float* __restrict__ out) {
  __shared__ __bf16 hlds[2][16][HH + 8];   // 272B rows: frag reads 2-way (free)
  const int tid  = threadIdx.x;
  const int wave = tid >> 6, lane = tid & 63;
  const int l15  = lane & 15, q = lane >> 4;
  const int bg = blockIdx.x, b0 = bg * 16;
  const int j = wave * 16 + l15;

  // Wh B-fragments: resident in registers for the whole scan (64 VGPR/lane)
  bf16x8 bfrag[4][4];
#pragma unroll
  for (int g = 0; g < 4; g++)
#pragma unroll
    for (int ks = 0; ks < 4; ks++)
      bfrag[g][ks] = *(const bf16x8*)(WhT + (size_t)(g * HH + j) * HH + ks * 32 + q * 8);

  bf16x8 zero8;
#pragma unroll
  for (int e = 0; e < 8; e++) zero8[e] = (__bf16)0.0f;
  const f32x4 fzero = {0.f, 0.f, 0.f, 0.f};

  float c_reg[4], nh_reg[4];
#pragma unroll
  for (int r = 0; r < 4; r++) {
    int b = b0 + q * 4 + r;
    c_reg[r] = c0[(size_t)b * HH + j];
    hlds[0][q * 4 + r][j] = (__bf16)h0[(size_t)b * HH + j];
  }
  __syncthreads();

  float* cT = out + (size_t)TT * BB * HH;
  float* hT = cT + (size_t)BB * HH;

  // prefetch slots for t=0 (slot A) and t=1 (slot B)
  uint2 xgbA[4], xgbB[4];
  int4 dn4A, dn4B;
  int dnAA, dnAB;
#pragma unroll
  for (int g = 0; g < 4; g++) {
    xgbA[g] = *(const uint2*)(Xg + ((size_t)bg * NG + g * HH + j) * 16 + q * 4);
    xgbB[g] = *(const uint2*)(Xg + (((size_t)16 + bg) * NG + g * HH + j) * 16 + q * 4);
  }
  dn4A = *(const int4*)(done + b0 + q * 4);
  dn4B = *(const int4*)(done + BB + b0 + q * 4);
  dnAA = done[b0 + l15];
  dnAB = done[BB + b0 + l15];

  auto do_step = [&](int t, uint2* xgs, int4& dn4s, int& dnAs) {
    // consume this slot
    uint2 xg_c[4];
#pragma unroll
    for (int g = 0; g < 4; g++) xg_c[g] = xgs[g];
    int4 dn4_c = dn4s;
    int dnA_c = dnAs;
    // refill slot with t+2 (in flight across the barrier; clamp at end)
    int tp = t + 2; if (tp >= TT) tp = TT - 1;
#pragma unroll
    for (int g = 0; g < 4; g++)
      xgs[g] = *(const uint2*)(Xg + (((size_t)tp * 16 + bg) * NG + g * HH + j) * 16 + q * 4);
    dn4s = *(const int4*)(done + tp * BB + b0 + q * 4);
    dnAs = done[tp * BB + b0 + l15];

    const int p = t & 1;
    // A-fragments: h state, m = lane&15 (batch-local); done-reset at consumption
    bf16x8 af[4];
#pragma unroll
    for (int ks = 0; ks < 4; ks++)
      af[ks] = *(const bf16x8*)&hlds[p][l15][ks * 32 + q * 8];
    if (dnA_c) {
#pragma unroll
      for (int ks = 0; ks < 4; ks++) af[ks] = zero8;
    }

    f32x4 acc[4];
#pragma unroll
    for (int g = 0; g < 4; g++) {
      acc[g] = fzero;
#pragma unroll
      for (int ks = 0; ks < 4; ks++)
        acc[g] = __builtin_amdgcn_mfma_f32_16x16x32_bf16(af[ks], bfrag[g][ks], acc[g], 0, 0, 0);
    }

    union { uint2 u; __bf16 h[4]; } ui, uf2, ug, uo;
    ui.u = xg_c[0]; uf2.u = xg_c[1]; ug.u = xg_c[2]; uo.u = xg_c[3];
    const int dnr[4] = {dn4_c.x, dn4_c.y, dn4_c.z, dn4_c.w};
#pragma unroll
    for (int r = 0; r < 4; r++) {
      float cprev = dnr[r] ? 0.0f : c_reg[r];
      float gi = acc[0][r] + (float)ui.h[r];
      float gf = acc[1][r] + (float)uf2.h[r];
      float gg = acc[2][r] + (float)ug.h[r];
      float go = acc[3][r] + (float)uo.h[r];
      float nc = fast_sig(gf) * cprev + fast_sig(gi) * fast_tanh(gg);
      float nh = fast_sig(go) * fast_tanh(nc);
      c_reg[r] = nc;
      nh_reg[r] = nh;
      out[((size_t)t * BB + b0 + q * 4 + r) * HH + j] = nh;   // posted, never drained
      hlds[1 - p][q * 4 + r][j] = (__bf16)nh;                 // write other buffer
    }
    lgkm_barrier();   // single barrier per step: LDS writes visible, vmcnt in flight
  };

  for (int t = 0; t < TT; t += 2) {
    do_step(t,     xgbA, dn4A, dnAA);
    do_step(t + 1, xgbB, dn4B, dnAB);
  }

#pragma unroll
  for (int r = 0; r < 4; r++) {
    cT[(size_t)(b0 + q * 4 + r) * HH + j] = c_reg[r];
    hT[(size_t)(b0 + q * 4 + r) * HH + j] = nh_reg[r];
  }
}

// ---------------- launch ----------------
extern "C" void kernel_launch(void* const* d_in, const int* in_sizes, int n_in,
                              void* d_out, int out_size, void* d_ws, size_t ws_size,
                              hipStream_t stream) {
  const float* c0   = (const float*)d_in[0];
  const float* h0   = (const float*)d_in[1];
  const float* obs  = (const float*)d_in[2];
  const int*   done = (const int*)d_in[3];
  const float* Wi   = (const float*)d_in[4];
  const float* Wh   = (const float*)d_in[5];
  const float* bias = (const float*)d_in[6];
  float* out = (float*)d_out;

  char* ws = (char*)d_ws;
  // ws layout: Xg bf16 [512][16][512][16] = 128 MiB; WiT 512 KiB; WhT 128 KiB
  __bf16* Xg  = (__bf16*)ws;
  __bf16* WiT = (__bf16*)(ws + (size_t)134217728);
  __bf16* WhT = (__bf16*)(ws + (size_t)134217728 + 524288);

  wconv_kernel<<<dim3(1024), dim3(256), 0, stream>>>(Wi, Wh, WiT, WhT);
  gemm_kernel<<<dim3(1024), dim3(512), 0, stream>>>(obs, WiT, bias, Xg);
  scan_kernel<<<dim3(16), dim3(512), 0, stream>>>(Xg, WhT, done, c0, h0, out);
}

// Round 3
// 799.624 us; speedup vs baseline: 1.3528x; 1.3528x over previous
//
#include <hip/hip_runtime.h>
#include <hip/hip_bf16.h>
#include <cstdint>
#include <cstddef>

// Problem constants
#define TT  512
#define BB  256
#define DIN 512
#define HH  128
#define NG  512   // 4*H

typedef __bf16 bf16x8 __attribute__((ext_vector_type(8)));
typedef float  f32x4  __attribute__((ext_vector_type(4)));

// ---- nonlinearities: 1 transcendental each ------------------------------
// P(s) ~= 1/(1+e) for e in (0,1], s = 2e-1. Chebyshev-derived (2/(3+s)
// expansion), max err ~4e-5. Verified: e=0.13534 -> 0.88081 (true 0.88081).
__device__ __forceinline__ float p_recip1p(float e) {
  float s = __builtin_fmaf(2.f, e, -1.f);
  float p = __builtin_fmaf(s, -0.00336424f, 0.00980413f);
  p = __builtin_fmaf(s, p, -0.0243654f);
  p = __builtin_fmaf(s, p, 0.0734565f);
  p = __builtin_fmaf(s, p, -0.222261f);
  p = __builtin_fmaf(s, p, 0.666706f);
  return p;
}
__device__ __forceinline__ float fast_sig(float x) {
  float e = __builtin_amdgcn_exp2f(-1.44269504f * __builtin_fabsf(x));
  float p = p_recip1p(e);                  // sigma(|x|)
  return x >= 0.f ? p : 1.f - p;
}
__device__ __forceinline__ float fast_tanh(float x) {
  float e = __builtin_amdgcn_exp2f(-2.88539008f * __builtin_fabsf(x));
  float t = __builtin_fmaf(2.f, p_recip1p(e), -1.f);   // tanh(|x|)
  return __builtin_copysignf(t, x);
}

// LDS-visibility-only barrier: vmcnt (global loads/stores) stays in flight.
__device__ __forceinline__ void lgkm_barrier() {
  asm volatile("s_waitcnt lgkmcnt(0)\n\ts_barrier" ::: "memory");
}

// ---------------- P0: weight transpose + fp32->bf16 convert ----------------
__global__ void wconv_kernel(const float* __restrict__ Wi, const float* __restrict__ Wh,
                             __bf16* __restrict__ WiT, __bf16* __restrict__ WhT) {
  int idx = blockIdx.x * 256 + threadIdx.x;
  if (idx < DIN * NG) {
    int n = idx >> 9, k = idx & 511;
    WiT[(size_t)n * DIN + k] = (__bf16)Wi[(size_t)k * NG + n];
  }
  if (idx < HH * NG) {
    int n = idx >> 7, k = idx & 127;
    WhT[(size_t)n * HH + k] = (__bf16)Wh[(size_t)k * NG + n];
  }
}

// ---------------- P1: Xg = obs @ Wi + b ------------------------------------
// Xg layout: [t][bg=16][r0=4][j=128][q=4][g=4] bf16 (128 MiB). Each scan
// block (bg,r0) reads a private contiguous 4KB/step; gates g contiguous.
// B (WiT) has zero intra-block reuse -> direct global loads (L2-resident),
// no LDS bounce. A staged via LDS with distance-2 register prefetch.
__global__ __launch_bounds__(512, 2)
void gemm_kernel(const float* __restrict__ obs, const __bf16* __restrict__ WiT,
                 const float* __restrict__ bias, __bf16* __restrict__ Xg) {
  __shared__ __bf16 Alds[128][40];
  const int tid  = threadIdx.x;
  const int wave = tid >> 6, lane = tid & 63;
  const int l15  = lane & 15, q = lane >> 4;
  const size_t m0 = (size_t)blockIdx.x * 128;

  const f32x4 fzero = {0.f, 0.f, 0.f, 0.f};
  f32x4 acc[8][4];
#pragma unroll
  for (int i = 0; i < 8; i++)
#pragma unroll
    for (int jj = 0; jj < 4; jj++) acc[i][jj] = fzero;

  const int am = tid >> 2, aq = tid & 3;
  const float* aptr = obs + (m0 + am) * DIN + aq * 8;
  const __bf16* bptr[4];
#pragma unroll
  for (int nt = 0; nt < 4; nt++)
    bptr[nt] = WiT + (size_t)(wave * 64 + nt * 16 + l15) * DIN + q * 8;

  // distance-2 slots
  float4 a0[2], a1[2];
  bf16x8 bs[2][4];
  a0[0] = *(const float4*)(aptr);      a1[0] = *(const float4*)(aptr + 4);
  a0[1] = *(const float4*)(aptr + 32); a1[1] = *(const float4*)(aptr + 36);
#pragma unroll
  for (int nt = 0; nt < 4; nt++) {
    bs[0][nt] = *(const bf16x8*)(bptr[nt]);
    bs[1][nt] = *(const bf16x8*)(bptr[nt] + 32);
  }

#pragma unroll
  for (int kc = 0; kc < DIN; kc += 32) {
    const int sl = (kc >> 5) & 1;
    if (kc) lgkm_barrier();            // prev frag reads drained
    { // stage A tile (consumes A slot sl)
      float4 f0 = a0[sl], f1 = a1[sl];
      bf16x8 v = {(__bf16)f0.x, (__bf16)f0.y, (__bf16)f0.z, (__bf16)f0.w,
                  (__bf16)f1.x, (__bf16)f1.y, (__bf16)f1.z, (__bf16)f1.w};
      *(bf16x8*)&Alds[am][aq * 8] = v;
    }
    lgkm_barrier();                    // A visible; vmcnt untouched
    int kp = kc + 64; if (kp > DIN - 32) kp = DIN - 32;   // clamped tail (unused)
    a0[sl] = *(const float4*)(aptr + kp);
    a1[sl] = *(const float4*)(aptr + kp + 4);
#pragma unroll
    for (int mt = 0; mt < 8; mt++) {
      bf16x8 af = *(const bf16x8*)&Alds[mt * 16 + l15][q * 8];
#pragma unroll
      for (int nt = 0; nt < 4; nt++)
        acc[mt][nt] = __builtin_amdgcn_mfma_f32_16x16x32_bf16(af, bs[sl][nt], acc[mt][nt], 0, 0, 0);
    }
#pragma unroll
    for (int nt = 0; nt < 4; nt++)     // refill B slot for kc+64
      bs[sl][nt] = *(const bf16x8*)(bptr[nt] + kp);
  }

  // epilogue: C row = mt*16 + q*4 + r; b = half*128 + row -> bg = half*8+mt, r0 = r
  const int t = blockIdx.x >> 1;
  const int half = blockIdx.x & 1;
#pragma unroll
  for (int mt = 0; mt < 8; mt++) {
    const int bg = half * 8 + mt;
#pragma unroll
    for (int nt = 0; nt < 4; nt++) {
      const int n = wave * 64 + nt * 16 + l15;
      const int g = n >> 7, jj = n & 127;
      const float bb = bias[n];
      __bf16* base = Xg + (size_t)(t * 16 + bg) * 4 * 2048 + jj * 16 + q * 4 + g;
#pragma unroll
      for (int r = 0; r < 4; r++)
        base[(size_t)r * 2048] = (__bf16)(acc[mt][nt][r] + bb);
    }
  }
}

// ---------------- P2: scan, 64 blocks = 16 batch-groups x 4 reg-slices -----
// Block (bg,R0) owns batch rows b0+{R0,4+R0,8+R0,12+R0} (the C-rows with
// reg==R0): elementwise is ONE full-lane pass. MFMA is 4x redundant (pipe
// was ~7% busy). h masked at write with next-step done (prefetched).
template<int R0>
__device__ __forceinline__ void scan_body(
    const __bf16* __restrict__ Xg, const __bf16* __restrict__ WhT,
    const int* __restrict__ done, const float* __restrict__ c0,
    const float* __restrict__ h0, float* __restrict__ out,
    int bg, __bf16 (*hlds)[16][HH + 8]) {
  const int tid  = threadIdx.x;
  const int wave = tid >> 6, lane = tid & 63;
  const int l15  = lane & 15, q = lane >> 4;
  const int b0 = bg * 16;
  const int j  = wave * 16 + l15;
  const int b  = b0 + q * 4 + R0;        // owned batch row
  const int row = q * 4 + R0;            // LDS row for owned batch

  // Wh B-fragments resident in registers (64 VGPR/lane)
  bf16x8 bfrag[4][4];
#pragma unroll
  for (int g = 0; g < 4; g++)
#pragma unroll
    for (int ks = 0; ks < 4; ks++)
      bfrag[g][ks] = *(const bf16x8*)(WhT + (size_t)(g * HH + j) * HH + ks * 32 + q * 8);

  // zero both h buffers (unowned rows stay 0 -> garbage C rows are finite)
  for (int i = tid; i < 2 * 16 * (HH + 8); i += 512) ((__bf16*)hlds)[i] = (__bf16)0.f;
  __syncthreads();
  const int d0 = done[b];
  float c = c0[(size_t)b * HH + j];
  hlds[0][row][j] = d0 ? (__bf16)0.f : (__bf16)h0[(size_t)b * HH + j];
  __syncthreads();

  const size_t tstride = (size_t)16 * 4 * 2048;   // Xg elems per timestep
  const __bf16* xpA = Xg + (size_t)(bg * 4 + R0) * 2048 + j * 16 + q * 4;
  const __bf16* xpB = xpA + tstride;
  const int* dpA = done + b;
  const int* dpB = dpA + BB;
  uint2 xgA = *(const uint2*)xpA;  xpA += 2 * tstride;
  uint2 xgB = *(const uint2*)xpB;  xpB += 2 * tstride;
  int dnA = *dpA; dpA += 2 * BB;
  int dnB = *dpB; dpB += 2 * BB;

  const f32x4 fz = {0.f, 0.f, 0.f, 0.f};
  float* op = out + (size_t)b * HH + j;
  float nh = 0.f;

  for (int t = 0; t < TT; t += 2) {
    // ---- step t (read hlds[0], write hlds[1], h-mask = done[t+1] = dnB) ----
    {
      uint2 xg_c = xgA; int dn_c = dnA, dn_w = dnB;
      if (t + 2 < TT) { xgA = *(const uint2*)xpA; dnA = *dpA; }
      xpA += 2 * tstride; dpA += 2 * BB;

      bf16x8 af[4];
#pragma unroll
      for (int ks = 0; ks < 4; ks++)
        af[ks] = *(const bf16x8*)&hlds[0][l15][ks * 32 + q * 8];
      union { uint2 u; __bf16 h[4]; } ux; ux.u = xg_c;
      f32x4 acc[4];
#pragma unroll
      for (int g = 0; g < 4; g++) {
        float xv = (float)ux.h[g];
        acc[g] = (f32x4){xv, xv, xv, xv};
#pragma unroll
        for (int ks = 0; ks < 4; ks++)
          acc[g] = __builtin_amdgcn_mfma_f32_16x16x32_bf16(af[ks], bfrag[g][ks], acc[g], 0, 0, 0);
      }
      float gi = acc[0][R0], gf = acc[1][R0], gg = acc[2][R0], go = acc[3][R0];
      float cprev = dn_c ? 0.f : c;
      float nc = __builtin_fmaf(fast_sig(gf), cprev, fast_sig(gi) * fast_tanh(gg));
      nh = fast_sig(go) * fast_tanh(nc);
      c = nc;
      *op = nh; op += BB * HH;
      hlds[1][row][j] = dn_w ? (__bf16)0.f : (__bf16)nh;
      lgkm_barrier();
    }
    // ---- step t+1 (read hlds[1], write hlds[0], h-mask = done[t+2] = dnA) --
    {
      uint2 xg_c = xgB; int dn_c = dnB, dn_w = dnA;
      if (t + 3 < TT) { xgB = *(const uint2*)xpB; dnB = *dpB; }
      xpB += 2 * tstride; dpB += 2 * BB;

      bf16x8 af[4];
#pragma unroll
      for (int ks = 0; ks < 4; ks++)
        af[ks] = *(const bf16x8*)&hlds[1][l15][ks * 32 + q * 8];
      union { uint2 u; __bf16 h[4]; } ux; ux.u = xg_c;
      f32x4 acc[4];
#pragma unroll
      for (int g = 0; g < 4; g++) {
        float xv = (float)ux.h[g];
        acc[g] = (f32x4){xv, xv, xv, xv};
#pragma unroll
        for (int ks = 0; ks < 4; ks++)
          acc[g] = __builtin_amdgcn_mfma_f32_16x16x32_bf16(af[ks], bfrag[g][ks], acc[g], 0, 0, 0);
      }
      float gi = acc[0][R0], gf = acc[1][R0], gg = acc[2][R0], go = acc[3][R0];
      float cprev = dn_c ? 0.f : c;
      float nc = __builtin_fmaf(fast_sig(gf), cprev, fast_sig(gi) * fast_tanh(gg));
      nh = fast_sig(go) * fast_tanh(nc);
      c = nc;
      *op = nh; op += BB * HH;
      hlds[0][row][j] = dn_w ? (__bf16)0.f : (__bf16)nh;
      lgkm_barrier();
    }
  }
  (void)fz;

  float* cT = out + (size_t)TT * BB * HH;
  float* hT = cT + (size_t)BB * HH;
  cT[(size_t)b * HH + j] = c;
  hT[(size_t)b * HH + j] = nh;
}

__global__ __launch_bounds__(512, 2)
void scan_kernel(const __bf16* __restrict__ Xg, const __bf16* __restrict__ WhT,
                 const int* __restrict__ done, const float* __restrict__ c0,
                 const float* __restrict__ h0, float* __restrict__ out) {
  __shared__ __bf16 hlds[2][16][HH + 8];
  const int bg = blockIdx.x >> 2;
  switch (blockIdx.x & 3) {
    case 0: scan_body<0>(Xg, WhT, done, c0, h0, out, bg, hlds); break;
    case 1: scan_body<1>(Xg, WhT, done, c0, h0, out, bg, hlds); break;
    case 2: scan_body<2>(Xg, WhT, done, c0, h0, out, bg, hlds); break;
    case 3: scan_body<3>(Xg, WhT, done, c0, h0, out, bg, hlds); break;
  }
}

// ---------------- launch ----------------
extern "C" void kernel_launch(void* const* d_in, const int* in_sizes, int n_in,
                              void* d_out, int out_size, void* d_ws, size_t ws_size,
                              hipStream_t stream) {
  const float* c0   = (const float*)d_in[0];
  const float* h0   = (const float*)d_in[1];
  const float* obs  = (const float*)d_in[2];
  const int*   done = (const int*)d_in[3];
  const float* Wi   = (const float*)d_in[4];
  const float* Wh   = (const float*)d_in[5];
  const float* bias = (const float*)d_in[6];
  float* out = (float*)d_out;

  char* ws = (char*)d_ws;
  // ws layout: Xg bf16 [512][16][4][128][4][4] = 128 MiB; WiT 512 KiB; WhT 128 KiB
  __bf16* Xg  = (__bf16*)ws;
  __bf16* WiT = (__bf16*)(ws + (size_t)134217728);
  __bf16* WhT = (__bf16*)(ws + (size_t)134217728 + 524288);

  wconv_kernel<<<dim3(1024), dim3(256), 0, stream>>>(Wi, Wh, WiT, WhT);
  gemm_kernel<<<dim3(1024), dim3(512), 0, stream>>>(obs, WiT, bias, Xg);
  scan_kernel<<<dim3(64), dim3(512), 0, stream>>>(Xg, WhT, done, c0, h0, out);
}